// Round 2
// baseline (376.900 us; speedup 1.0000x reference)
//
#include <hip/hip_runtime.h>

#define NATOMS 4096
#define BOXF 44.0f
#define INV_BOX (1.0f / 44.0f)
#define CUT2 (17.5f * 17.5f)

// One wave (64 lanes) per atom i; lanes stride over j.
// Energy: E = 0.5 * sum_{ordered pairs} s_ij * pe_ij
// Force:  f_i = sum_j s_ij * pe'(d_ij)/d_ij * r_ij * [r2 > 1]
// where s_ij = 0 if (i^j)&511 == 0 or d >= cutoff; else 1 same block, 2 cross block.
__global__ __launch_bounds__(256) void bmh_kernel(
    const float* __restrict__ coords,
    const float* __restrict__ Am,
    const float* __restrict__ Cm,
    const float* __restrict__ Dm,
    const float* __restrict__ Rm,
    const float* __restrict__ Sm,
    float* __restrict__ out, int n)
{
    __shared__ float lx[NATOMS], ly[NATOMS], lz[NATOMS];

    // Stage coords into LDS (SoA)
    for (int idx = threadIdx.x; idx < n * 3; idx += blockDim.x) {
        float v = coords[idx];
        int atom = idx / 3;
        int c = idx - 3 * atom;
        float* dst = (c == 0) ? lx : (c == 1) ? ly : lz;
        dst[atom] = v;
    }
    __syncthreads();

    const int wave = threadIdx.x >> 6;
    const int lane = threadIdx.x & 63;
    const int i = blockIdx.x * (blockDim.x >> 6) + wave;

    const float xi = lx[i], yi = ly[i], zi = lz[i];
    const size_t row = (size_t)i * (size_t)n;

    float e = 0.0f, fx = 0.0f, fy = 0.0f, fz = 0.0f;

    #pragma unroll 4
    for (int j0 = 0; j0 < n; j0 += 64) {
        const int j = j0 + lane;
        // issue all 5 param loads early (independent of compute)
        const float a  = Am[row + j];
        const float c_ = Cm[row + j];
        const float dd = Dm[row + j];
        const float rh = Rm[row + j];
        const float sg = Sm[row + j];

        float dx = xi - lx[j];
        float dy = yi - ly[j];
        float dz = zi - lz[j];
        dx -= BOXF * rintf(dx * INV_BOX);   // rintf = round-half-even, matches jnp.round
        dy -= BOXF * rintf(dy * INV_BOX);
        dz -= BOXF * rintf(dz * INV_BOX);
        const float r2 = dx * dx + dy * dy + dz * dz;

        const int x = i ^ j;
        const bool locdiff = (x & 511) != 0;   // loc_i != loc_j (also kills i==j)

        if (r2 < CUT2 && locdiff) {
            const float s = (x >> 9) ? 2.0f : 1.0f;   // cross-block pairs weighted 2
            const float d2c = fmaxf(r2, 1.0f);
            const float d = sqrtf(d2c);
            const float inv_d2 = 1.0f / d2c;
            const float inv_rh = 1.0f / rh;
            const float ex = __expf((sg - d) * inv_rh);
            const float i6 = inv_d2 * inv_d2 * inv_d2;
            const float i8 = i6 * inv_d2;
            // pe = a*ex - c/d^6 + dd/d^8
            const float pe = fmaf(a, ex, fmaf(dd, i8, -c_ * i6));
            e += s * pe;
            if (r2 > 1.0f) {   // clamp region has zero coord-gradient
                const float inv_d = d * inv_d2;  // 1/d
                // pe'(d)/d = -a*ex/(rh*d) + 6c/d^8 - 8dd/d^10
                const float gpd = fmaf(6.0f * c_, i8,
                                  fmaf(-8.0f * dd, i8 * inv_d2,
                                       -a * ex * inv_rh * inv_d));
                const float g = s * gpd;
                fx = fmaf(g, dx, fx);
                fy = fmaf(g, dy, fy);
                fz = fmaf(g, dz, fz);
            }
        }
    }

    // wave-level reduction (64 lanes)
    for (int off = 32; off; off >>= 1) {
        e  += __shfl_down(e, off);
        fx += __shfl_down(fx, off);
        fy += __shfl_down(fy, off);
        fz += __shfl_down(fz, off);
    }

    if (lane == 0) {
        out[1 + 3 * i + 0] = fx;
        out[1 + 3 * i + 1] = fy;
        out[1 + 3 * i + 2] = fz;
        atomicAdd(out, 0.5f * e);
    }
}

extern "C" void kernel_launch(void* const* d_in, const int* in_sizes, int n_in,
                              void* d_out, int out_size, void* d_ws, size_t ws_size,
                              hipStream_t stream) {
    const float* coords = (const float*)d_in[0];
    // d_in[1] = q (charges) -- unused by the reference energy
    const float* Am = (const float*)d_in[2];
    const float* Cm = (const float*)d_in[3];
    const float* Dm = (const float*)d_in[4];
    const float* Rm = (const float*)d_in[5];
    const float* Sm = (const float*)d_in[6];
    float* out = (float*)d_out;

    const int n = in_sizes[1];  // N atoms (q has N elements)

    // zero the energy accumulator (forces are fully overwritten)
    hipMemsetAsync(d_out, 0, sizeof(float), stream);

    const int wavesPerBlock = 4;  // 256 threads
    dim3 grid(n / wavesPerBlock);
    bmh_kernel<<<grid, 256, 0, stream>>>(coords, Am, Cm, Dm, Rm, Sm, out, n);
}

// Round 3
// 349.195 us; speedup vs baseline: 1.0793x; 1.0793x over previous
//
#include <hip/hip_runtime.h>

#define NATOMS 4096
#define BOXF 44.0f
#define INV_BOX (1.0f / 44.0f)
#define CUT2 (17.5f * 17.5f)
#define WPR 2                 // waves (j-halves) per row
#define JSPAN (NATOMS / WPR)  // 2048

// block = 256 threads = 4 waves = 4 consecutive rows, all processing the SAME
// j-half (so the block stages only JSPAN coords in LDS = 24 KB).
// Each lane handles 4 consecutive j via float4 loads (branchless body).
// E = 0.5 * sum_{ordered p!=q} s_pq * pe;  s = 0 if loc equal, 1 same 512-block, 2 cross.
// f_i = sum_j s_ij * pe'(d)/d * r_ij * [r2 > 1]   (forces = +dE/dx, per reference)
__global__ __launch_bounds__(256) void bmh_kernel(
    const float* __restrict__ coords,
    const float* __restrict__ Am,
    const float* __restrict__ Cm,
    const float* __restrict__ Dm,
    const float* __restrict__ Rm,
    const float* __restrict__ Sm,
    float* __restrict__ out, int n)
{
    __shared__ __align__(16) float lx[JSPAN];
    __shared__ __align__(16) float ly[JSPAN];
    __shared__ __align__(16) float lz[JSPAN];

    const int half   = blockIdx.x & (WPR - 1);
    const int rowg   = blockIdx.x >> 1;       // group of 4 rows
    const int jstart = half * JSPAN;

    // stage this half's coords (SoA) into LDS
    for (int t = threadIdx.x; t < JSPAN; t += blockDim.x) {
        const int j = jstart + t;
        lx[t] = coords[3 * j];
        ly[t] = coords[3 * j + 1];
        lz[t] = coords[3 * j + 2];
    }
    __syncthreads();

    const int wave = threadIdx.x >> 6;
    const int lane = threadIdx.x & 63;
    const int i = rowg * 4 + wave;

    const float xi = coords[3 * i];
    const float yi = coords[3 * i + 1];
    const float zi = coords[3 * i + 2];
    const size_t row = (size_t)i * (size_t)n + (size_t)jstart;

    float e = 0.f, fx = 0.f, fy = 0.f, fz = 0.f;

    #pragma unroll 2
    for (int t0 = 0; t0 < JSPAN; t0 += 256) {
        const int tb = t0 + 4 * lane;   // local j offset (multiple of 4 -> 16B aligned)
        const int jb = jstart + tb;     // global j of element 0

        const float4 a4 = *(const float4*)(Am + row + tb);
        const float4 c4 = *(const float4*)(Cm + row + tb);
        const float4 d4 = *(const float4*)(Dm + row + tb);
        const float4 r4 = *(const float4*)(Rm + row + tb);
        const float4 s4 = *(const float4*)(Sm + row + tb);
        const float4 qx = *(const float4*)(lx + tb);
        const float4 qy = *(const float4*)(ly + tb);
        const float4 qz = *(const float4*)(lz + tb);

        const float av[4] = {a4.x, a4.y, a4.z, a4.w};
        const float cv[4] = {c4.x, c4.y, c4.z, c4.w};
        const float dv[4] = {d4.x, d4.y, d4.z, d4.w};
        const float rv[4] = {r4.x, r4.y, r4.z, r4.w};
        const float sv[4] = {s4.x, s4.y, s4.z, s4.w};
        const float xv[4] = {qx.x, qx.y, qx.z, qx.w};
        const float yv[4] = {qy.x, qy.y, qy.z, qy.w};
        const float zv[4] = {qz.x, qz.y, qz.z, qz.w};

        #pragma unroll
        for (int k = 0; k < 4; ++k) {
            float dx = xi - xv[k];
            float dy = yi - yv[k];
            float dz = zi - zv[k];
            dx -= BOXF * rintf(dx * INV_BOX);   // rintf = round-half-even = jnp.round
            dy -= BOXF * rintf(dy * INV_BOX);
            dz -= BOXF * rintf(dz * INV_BOX);
            const float r2 = fmaf(dx, dx, fmaf(dy, dy, dz * dz));

            const int xr = i ^ (jb + k);
            float w = (xr >> 9) ? 2.0f : 1.0f;                    // cross-block scale
            w = (((xr & 511) != 0) && (r2 < CUT2)) ? w : 0.0f;    // loc mask + cutoff

            const float d2c   = fmaxf(r2, 1.0f);
            const float inv_d2 = __builtin_amdgcn_rcpf(d2c);
            const float d      = sqrtf(d2c);
            const float inv_rh = __builtin_amdgcn_rcpf(rv[k]);
            const float ex     = __expf((sv[k] - d) * inv_rh);
            const float i6 = inv_d2 * inv_d2 * inv_d2;
            const float i8 = i6 * inv_d2;
            // pe = a*ex - c/d^6 + D/d^8
            const float pe = fmaf(av[k], ex, fmaf(dv[k], i8, -cv[k] * i6));
            e = fmaf(w, pe, e);

            const float inv_d = d * inv_d2;   // 1/d
            // pe'(d)/d = -a*ex/(rho*d) + 6c/d^8 - 8D/d^10
            const float gpd = fmaf(6.0f * cv[k], i8,
                               fmaf(-8.0f * dv[k], i8 * inv_d2,
                                    -av[k] * ex * inv_rh * inv_d));
            const float g = (r2 > 1.0f) ? w * gpd : 0.0f;   // clamp region: zero grad
            fx = fmaf(g, dx, fx);
            fy = fmaf(g, dy, fy);
            fz = fmaf(g, dz, fz);
        }
    }

    // wave-level reduction (64 lanes)
    for (int off = 32; off; off >>= 1) {
        e  += __shfl_down(e, off);
        fx += __shfl_down(fx, off);
        fy += __shfl_down(fy, off);
        fz += __shfl_down(fz, off);
    }

    if (lane == 0) {
        atomicAdd(out + 1 + 3 * i + 0, fx);
        atomicAdd(out + 1 + 3 * i + 1, fy);
        atomicAdd(out + 1 + 3 * i + 2, fz);
        atomicAdd(out, 0.5f * e);
    }
}

extern "C" void kernel_launch(void* const* d_in, const int* in_sizes, int n_in,
                              void* d_out, int out_size, void* d_ws, size_t ws_size,
                              hipStream_t stream) {
    const float* coords = (const float*)d_in[0];
    // d_in[1] = q (charges) -- unused by the reference energy
    const float* Am = (const float*)d_in[2];
    const float* Cm = (const float*)d_in[3];
    const float* Dm = (const float*)d_in[4];
    const float* Rm = (const float*)d_in[5];
    const float* Sm = (const float*)d_in[6];
    float* out = (float*)d_out;

    const int n = in_sizes[1];  // N atoms

    // zero all outputs (energy + forces are accumulated via atomics)
    hipMemsetAsync(d_out, 0, (size_t)out_size * sizeof(float), stream);

    dim3 grid(n / 4 * WPR);     // 4 rows per block, WPR j-halves
    bmh_kernel<<<grid, 256, 0, stream>>>(coords, Am, Cm, Dm, Rm, Sm, out, n);
}